// Round 10
// baseline (240.312 us; speedup 1.0000x reference)
//
#include <hip/hip_runtime.h>
#include <math.h>

typedef _Float16 f16;
typedef _Float16 f16x8 __attribute__((ext_vector_type(8)));
typedef float    f32x16 __attribute__((ext_vector_type(16)));
typedef unsigned int uint;
typedef unsigned short u16;

#define B_Q     1024
#define DIM     128
#define N_KEYS  100000
#define NPAD    102400          /* padded to 3200 groups of 32 */
#define NGP     (NPAD / 32)     /* 3200 groups */
#define GPC     16              /* groups per chunk (512 keys) */
#define NCHUNK  (NGP / GPC)     /* 200 chunks, 25 per XCD */
#define N_CLS   1000
#define QSCALE  11.541560327111707f /* 8/ln2: fold beta*log2(e) into queries */
#define CSUM    10
#define NCB     (N_CLS / CSUM)  /* 100 */

// ---- label histogram ----
__global__ void k_hist(const int* __restrict__ labels, uint* __restrict__ ghist) {
    __shared__ uint lh[N_CLS];
    for (int i = threadIdx.x; i < N_CLS; i += blockDim.x) lh[i] = 0;
    __syncthreads();
    const int stride = gridDim.x * blockDim.x;
    for (int i = blockIdx.x * blockDim.x + threadIdx.x; i < N_KEYS; i += stride)
        atomicAdd(&lh[labels[i]], 1u);
    __syncthreads();
    for (int i = threadIdx.x; i < N_CLS; i += blockDim.x)
        if (lh[i]) atomicAdd(&ghist[i], lh[i]);
}

// ---- exclusive scan -> cursor ----
__global__ void k_scan(const uint* __restrict__ ghist, uint* __restrict__ cursor) {
    __shared__ uint s[1024];
    const int t = threadIdx.x;
    const uint v = (t < N_CLS) ? ghist[t] : 0u;
    s[t] = v; __syncthreads();
    for (int o = 1; o < 1024; o <<= 1) {
        const uint x = (t >= o) ? s[t - o] : 0u;
        __syncthreads();
        s[t] += x;
        __syncthreads();
    }
    if (t < N_CLS) cursor[t] = s[t] - v;
}

// ---- fused prep: normalize, f16, scatter into MFMA-fragment order; dummies ----
__global__ void k_prep(const float* __restrict__ qm, const float* __restrict__ km,
                       const int* __restrict__ labels, uint* __restrict__ cursor,
                       f16* __restrict__ kf2, f16* __restrict__ qf2,
                       u16* __restrict__ kcls) {
    const int gid  = blockIdx.x * blockDim.x + threadIdx.x;
    const int n    = gid >> 6;
    const int lane = threadIdx.x & 63;
    if (n >= NPAD + B_Q) return;
    const bool isq   = n >= NPAD;
    const bool dummy = !isq && n >= N_KEYS;

    float a = 0.0f, b = 0.0f;
    if (!dummy) {
        const float* row = isq ? qm + (size_t)(n - NPAD) * DIM
                               : km + (size_t)n * DIM;
        a = row[lane]; b = row[lane + 64];
    }
    float ss = a * a + b * b;
    #pragma unroll
    for (int o = 32; o >= 1; o >>= 1) ss += __shfl_xor(ss, o);
    const float rn = (isq ? QSCALE : 1.0f) / fmaxf(sqrtf(ss), 1e-12f);

    int pos;
    if (isq)        pos = n - NPAD;
    else if (dummy) { pos = n; if (lane == 0) kcls[pos] = (u16)N_CLS; }
    else {
        const int lab = labels[n];
        if (lane == 0) pos = (int)atomicAdd(&cursor[lab], 1u);
        pos = __shfl(pos, 0);
        if (lane == 0) kcls[pos] = (u16)lab;
    }

    const float va = a * rn, vb = b * rn;   // dummy rows stay exactly 0
    f16x8 hv;
    #pragma unroll
    for (int j = 0; j < 8; ++j) {
        const int src = (lane & 15) * 8 + j;        // 0..127
        const float xa = __shfl(va, src & 63);
        const float xb = __shfl(vb, src & 63);
        hv[j] = (f16)((src < 64) ? xa : xb);
    }
    if (lane < 16) {
        f16* dst = isq ? qf2 : kf2;
        const int kk  = lane >> 1;
        const int lhi = lane & 1;
        *(f16x8*)(dst + (size_t)(pos >> 5) * 4096 + kk * 512 +
                  ((lhi << 5) + (pos & 31)) * 8) = hv;
    }
}

// ---- per-group class metadata: ca | cb<<11 | split<<22 (<=2 runs/group) ----
__global__ void k_meta(const u16* __restrict__ kcls, int* __restrict__ meta) {
    const int gid  = blockIdx.x * blockDim.x + threadIdx.x;
    const int g    = gid >> 6;
    const int lane = threadIdx.x & 63;
    if (g >= NGP) return;
    const int  cl = kcls[g * 32 + (lane & 31)];
    const int  ca = __shfl(cl, 0);
    const uint dm = (uint)(__ballot(cl != ca) & 0xffffffffull);
    const int  split = dm ? (__ffs(dm) - 1) : 32;
    const int  cb = (split < 32) ? __shfl(cl, split) : ca;
    if (lane == 0) meta[g] = ca | (cb << 11) | (split << 22);
}

// ---- main (ablation-templated): barrier-free, LDS-free.
// MODE 0: loads+MFMA only. MODE 1: +exp2/sums. MODE 2: full (round-9 exact).
#define FLUSH(C) {                                                            \
    _Pragma("unroll")                                                         \
    for (int r = 0; r < 16; ++r) {                                            \
        float t0 = sums0[r], t1 = sums1[r];                                   \
        t0 += __shfl_xor(t0,1); t0 += __shfl_xor(t0,2); t0 += __shfl_xor(t0,4);\
        t0 += __shfl_xor(t0,8); t0 += __shfl_xor(t0,16);                      \
        t1 += __shfl_xor(t1,1); t1 += __shfl_xor(t1,2); t1 += __shfl_xor(t1,4);\
        t1 += __shfl_xor(t1,8); t1 += __shfl_xor(t1,16);                      \
        const int row = (r & 3) + 8 * (r >> 2) + 4 * lhi;                     \
        if (l31 == row) {                                                     \
            atomicAdd(&out_t[(size_t)(C) * B_Q + q00 + row], t0);             \
            atomicAdd(&out_t[(size_t)(C) * B_Q + q01 + row], t1);             \
        }                                                                     \
    } }
#define ZEROSUMS { _Pragma("unroll") for (int r=0;r<16;++r){sums0[r]=0.f;sums1[r]=0.f;} }

template<int MODE>
__global__ __launch_bounds__(256, 2)
void class_gemm5t(const f16* __restrict__ kf2, const f16* __restrict__ qf2,
                  const int* __restrict__ meta, float* __restrict__ out_t,
                  float* __restrict__ dbg) {
    const int tid  = threadIdx.x;
    const int w    = tid >> 6;
    const int lane = tid & 63;
    const int l31  = lane & 31;
    const int lhi  = lane >> 5;

    const int b     = blockIdx.x;
    const int xcd   = b & 7;
    const int s     = b >> 3;               // 0..99
    const int chunk = xcd * (NCHUNK / 8) + (s >> 2);
    const int qquad = s & 3;
    const int g0    = chunk * GPC;

    f16x8 A0[8], A1[8];
    {
        const f16* qa = qf2 + (size_t)(qquad * 8 + w * 2) * 4096 + lane * 8;
        #pragma unroll
        for (int kk = 0; kk < 8; ++kk) {
            A0[kk] = *(const f16x8*)(qa + kk * 512);
            A1[kk] = *(const f16x8*)(qa + 4096 + kk * 512);
        }
    }
    const int q00 = qquad * 256 + w * 64;
    const int q01 = q00 + 32;

    int mv = 0;
    if constexpr (MODE == 2) mv = meta[g0 + (lane & 15)];

    float sums0[16], sums1[16];
    ZEROSUMS;
    int cur = -1;
    float acc = 0.0f;

    for (int i = 0; i < GPC; ++i) {
        const f16* base = kf2 + (size_t)(g0 + i) * 4096 + lane * 8;
        f32x16 c0 = {}, c1 = {};
        #pragma unroll
        for (int kk = 0; kk < 8; ++kk) {
            const f16x8 Bf = *(const f16x8*)(base + kk * 512);
            c0 = __builtin_amdgcn_mfma_f32_32x32x16_f16(A0[kk], Bf, c0, 0, 0, 0);
            c1 = __builtin_amdgcn_mfma_f32_32x32x16_f16(A1[kk], Bf, c1, 0, 0, 0);
        }

        if constexpr (MODE == 0) {
            acc += c0[0] + c1[0];            // keep MFMA+loads live, minimal VALU
        } else if constexpr (MODE == 1) {
            #pragma unroll
            for (int r = 0; r < 16; ++r) {
                sums0[r] += __builtin_amdgcn_exp2f(c0[r]);
                sums1[r] += __builtin_amdgcn_exp2f(c1[r]);
            }
        } else {
            const int m     = __shfl(mv, i);
            const int ca    = m & 0x7FF;
            const int cb    = (m >> 11) & 0x7FF;
            const int split = m >> 22;

            if (ca != cur) {
                if (cur >= 0) FLUSH(cur);
                ZEROSUMS;
                cur = ca;
            }
            if (split == 32) {
                #pragma unroll
                for (int r = 0; r < 16; ++r) {
                    sums0[r] += __builtin_amdgcn_exp2f(c0[r]);
                    sums1[r] += __builtin_amdgcn_exp2f(c1[r]);
                }
            } else {
                const bool lo = l31 < split;
                #pragma unroll
                for (int r = 0; r < 16; ++r) {
                    sums0[r] += lo ? __builtin_amdgcn_exp2f(c0[r]) : 0.0f;
                    sums1[r] += lo ? __builtin_amdgcn_exp2f(c1[r]) : 0.0f;
                }
                FLUSH(cur);
                ZEROSUMS;
                cur = cb;
                #pragma unroll
                for (int r = 0; r < 16; ++r) {
                    sums0[r] += lo ? 0.0f : __builtin_amdgcn_exp2f(c0[r]);
                    sums1[r] += lo ? 0.0f : __builtin_amdgcn_exp2f(c1[r]);
                }
            }
        }
    }

    if constexpr (MODE == 2) {
        if (cur >= 0) FLUSH(cur);
    } else {
        if constexpr (MODE == 1) {
            #pragma unroll
            for (int r = 0; r < 16; ++r) acc += sums0[r] + sums1[r];
        }
        dbg[(size_t)b * 256 + tid] = acc;    // keep everything live
    }
}

// ---- epilogue 1: partial class-sums per query (100 blocks x 1024 thr) ----
__global__ __launch_bounds__(1024)
void k_qsum(const float* __restrict__ out_t, float* __restrict__ partial) {
    const int cb = blockIdx.x;
    const int q  = threadIdx.x;
    const float* p = out_t + (size_t)cb * CSUM * B_Q + q;
    float s = 0.0f;
    #pragma unroll
    for (int i = 0; i < CSUM; ++i) s += p[(size_t)i * B_Q];
    partial[cb * B_Q + q] = s;
}

// ---- epilogue 2: 64x64 scaled transpose tiles ----
__global__ __launch_bounds__(256)
void k_norm_t(const float* __restrict__ out_t, const float* __restrict__ partial,
              float* __restrict__ out) {
    __shared__ float tile[64 * 65];
    __shared__ float invq[64];
    const int tid  = threadIdx.x;
    const int w    = tid >> 6;
    const int lane = tid & 63;
    const int q0   = blockIdx.x * 64;
    const int c0   = blockIdx.y * 64;

    if (tid < 64) {
        float s = 0.0f;
        for (int cb = 0; cb < NCB; ++cb) s += partial[cb * B_Q + q0 + tid];
        invq[tid] = 1.0f / s;
    }
    #pragma unroll
    for (int i = 0; i < 16; ++i) {
        const int cidx = c0 + w * 16 + i;
        const float v = (cidx < N_CLS) ? out_t[(size_t)cidx * B_Q + q0 + lane] : 0.0f;
        tile[lane * 65 + w * 16 + i] = v;
    }
    __syncthreads();
    #pragma unroll
    for (int j = 0; j < 16; ++j) {
        const int r    = w * 16 + j;
        const int cidx = c0 + lane;
        if (cidx < N_CLS)
            out[(size_t)(q0 + r) * N_CLS + cidx] = tile[r * 65 + lane] * invq[r];
    }
}

extern "C" void kernel_launch(void* const* d_in, const int* in_sizes, int n_in,
                              void* d_out, int out_size, void* d_ws, size_t ws_size,
                              hipStream_t stream) {
    const float* qm     = (const float*)d_in[0];
    const float* km     = (const float*)d_in[1];
    const int*   labels = (const int*)d_in[2];
    float* out = (float*)d_out;

    char* p = (char*)d_ws;
    f16*   kf2     = (f16*)p;   p += (size_t)NPAD * DIM * 2;        // 26.2 MB
    f16*   qf2     = (f16*)p;   p += (size_t)B_Q * DIM * 2;         // 256 KB
    float* out_t   = (float*)p; p += (size_t)N_CLS * B_Q * 4;       // 4.1 MB
    // NOTE: class-1000 (dummy) bucket row == out_t + 1000*B_Q == partial base.
    float* partial = (float*)p; p += (size_t)NCB * B_Q * 4;         // 400 KB
    uint*  ghist   = (uint*)p;  p += N_CLS * 4;
    uint*  cursor  = (uint*)p;  p += N_CLS * 4;
    u16*   kcls    = (u16*)p;   p += (size_t)NPAD * 2;              // 205 KB
    int*   meta    = (int*)p;   p += (size_t)NGP * 4;               // 12.8 KB

    hipMemsetAsync(ghist, 0, N_CLS * sizeof(uint), stream);

    hipLaunchKernelGGL(k_hist, dim3(128), dim3(256), 0, stream, labels, ghist);
    hipLaunchKernelGGL(k_scan, dim3(1), dim3(1024), 0, stream, ghist, cursor);

    const int prows = NPAD + B_Q;                  // keys + dummies + queries
    hipLaunchKernelGGL(k_prep, dim3((prows * 64 + 255) / 256), dim3(256), 0, stream,
                       qm, km, labels, cursor, kf2, qf2, kcls);
    hipLaunchKernelGGL(k_meta, dim3((NGP * 64 + 255) / 256), dim3(256), 0, stream,
                       kcls, meta);

    // ---- ablation probes (dbg -> out_t region, re-zeroed before the real run)
    float* dbg = out_t;    // 800*256 floats = 819 KB << 4.1 MB region
    class_gemm5t<0><<<dim3(4 * NCHUNK), dim3(256), 0, stream>>>(kf2, qf2, meta, out_t, dbg);
    class_gemm5t<1><<<dim3(4 * NCHUNK), dim3(256), 0, stream>>>(kf2, qf2, meta, out_t, dbg);

    hipMemsetAsync(out_t, 0, (size_t)N_CLS * B_Q * sizeof(float), stream);

    // ---- real run (round-9 exact semantics)
    class_gemm5t<2><<<dim3(4 * NCHUNK), dim3(256), 0, stream>>>(kf2, qf2, meta, out_t, dbg);

    hipLaunchKernelGGL(k_qsum, dim3(NCB), dim3(1024), 0, stream, out_t, partial);
    hipLaunchKernelGGL(k_norm_t, dim3(B_Q / 64, (N_CLS + 63) / 64), dim3(256), 0, stream,
                       out_t, partial, out);
}

// Round 11
// 124.954 us; speedup vs baseline: 1.9232x; 1.9232x over previous
//
#include <hip/hip_runtime.h>
#include <math.h>

typedef _Float16 f16;
typedef _Float16 f16x8 __attribute__((ext_vector_type(8)));
typedef float    f32x16 __attribute__((ext_vector_type(16)));
typedef unsigned int uint;
typedef unsigned short u16;

#define B_Q     1024
#define DIM     128
#define N_KEYS  100000
#define NPAD    102400          /* padded to 3200 groups of 32 */
#define NGP     (NPAD / 32)     /* 3200 groups */
#define GPC     16              /* groups per chunk (512 keys) */
#define NCHUNK  (NGP / GPC)     /* 200 chunks, 25 per XCD */
#define N_CLS   1000
#define QSCALE  11.541560327111707f /* 8/ln2: fold beta*log2(e) into queries */
#define CSUM    10
#define NCB     (N_CLS / CSUM)  /* 100 */

// ---- label histogram ----
__global__ void k_hist(const int* __restrict__ labels, uint* __restrict__ ghist) {
    __shared__ uint lh[N_CLS];
    for (int i = threadIdx.x; i < N_CLS; i += blockDim.x) lh[i] = 0;
    __syncthreads();
    const int stride = gridDim.x * blockDim.x;
    for (int i = blockIdx.x * blockDim.x + threadIdx.x; i < N_KEYS; i += stride)
        atomicAdd(&lh[labels[i]], 1u);
    __syncthreads();
    for (int i = threadIdx.x; i < N_CLS; i += blockDim.x)
        if (lh[i]) atomicAdd(&ghist[i], lh[i]);
}

// ---- exclusive scan -> cursor ----
__global__ void k_scan(const uint* __restrict__ ghist, uint* __restrict__ cursor) {
    __shared__ uint s[1024];
    const int t = threadIdx.x;
    const uint v = (t < N_CLS) ? ghist[t] : 0u;
    s[t] = v; __syncthreads();
    for (int o = 1; o < 1024; o <<= 1) {
        const uint x = (t >= o) ? s[t - o] : 0u;
        __syncthreads();
        s[t] += x;
        __syncthreads();
    }
    if (t < N_CLS) cursor[t] = s[t] - v;
}

// ---- fused prep: normalize, f16, scatter into MFMA-fragment order; dummies ----
// layout per 32-row group: [kk(8)][lane(64)][j(8)] f16; (kk,lane,j) =
// row (lane&31), dim kk*16 + (lane>>5)*8 + j. (A/B operand layouts are
// lane-symmetric, so the same layout serves K-as-A and Q-as-B.)
__global__ void k_prep(const float* __restrict__ qm, const float* __restrict__ km,
                       const int* __restrict__ labels, uint* __restrict__ cursor,
                       f16* __restrict__ kf2, f16* __restrict__ qf2,
                       u16* __restrict__ kcls) {
    const int gid  = blockIdx.x * blockDim.x + threadIdx.x;
    const int n    = gid >> 6;
    const int lane = threadIdx.x & 63;
    if (n >= NPAD + B_Q) return;
    const bool isq   = n >= NPAD;
    const bool dummy = !isq && n >= N_KEYS;

    float a = 0.0f, b = 0.0f;
    if (!dummy) {
        const float* row = isq ? qm + (size_t)(n - NPAD) * DIM
                               : km + (size_t)n * DIM;
        a = row[lane]; b = row[lane + 64];
    }
    float ss = a * a + b * b;
    #pragma unroll
    for (int o = 32; o >= 1; o >>= 1) ss += __shfl_xor(ss, o);
    const float rn = (isq ? QSCALE : 1.0f) / fmaxf(sqrtf(ss), 1e-12f);

    int pos;
    if (isq)        pos = n - NPAD;
    else if (dummy) { pos = n; if (lane == 0) kcls[pos] = (u16)N_CLS; }
    else {
        const int lab = labels[n];
        if (lane == 0) pos = (int)atomicAdd(&cursor[lab], 1u);
        pos = __shfl(pos, 0);
        if (lane == 0) kcls[pos] = (u16)lab;
    }

    const float va = a * rn, vb = b * rn;   // dummy rows stay exactly 0
    f16x8 hv;
    #pragma unroll
    for (int j = 0; j < 8; ++j) {
        const int src = (lane & 15) * 8 + j;        // 0..127
        const float xa = __shfl(va, src & 63);
        const float xb = __shfl(vb, src & 63);
        hv[j] = (f16)((src < 64) ? xa : xb);
    }
    if (lane < 16) {
        f16* dst = isq ? qf2 : kf2;
        const int kk  = lane >> 1;
        const int lhi = lane & 1;
        *(f16x8*)(dst + (size_t)(pos >> 5) * 4096 + kk * 512 +
                  ((lhi << 5) + (pos & 31)) * 8) = hv;
    }
}

// ---- per-group class metadata: ca | cb<<11 | split<<22 (<=2 runs/group) ----
__global__ void k_meta(const u16* __restrict__ kcls, int* __restrict__ meta) {
    const int gid  = blockIdx.x * blockDim.x + threadIdx.x;
    const int g    = gid >> 6;
    const int lane = threadIdx.x & 63;
    if (g >= NGP) return;
    const int  cl = kcls[g * 32 + (lane & 31)];
    const int  ca = __shfl(cl, 0);
    const uint dm = (uint)(__ballot(cl != ca) & 0xffffffffull);
    const int  split = dm ? (__ffs(dm) - 1) : 32;
    const int  cb = (split < 32) ? __shfl(cl, split) : ca;
    if (lane == 0) meta[g] = ca | (cb << 11) | (split << 22);
}

// ---- main: SWAPPED-OPERAND MFMA. D = K_frag x Q_frag -> D[key][q]:
// col = lane&31 = QUERY (lane-local), rows = keys. Segment-sum over keys is
// per-lane scalar adds; flush = 1 shfl_xor(32) + 1 atomicAdd per subtile.
// Barrier-free, LDS-free; 800 blocks x 4 independent waves; keys streamed
// from global (fragment-ordered, coalesced dwordx4); XCD co-located chunks.
// [Ablation r10: loads+MFMA ~22us, +exp2 ~31us, old butterfly-flush V2 117us
//  -> flush machinery was 73% (codegen/regalloc, 76 VGPR collapse). This
//  structure deletes it.]
#define FLUSH2(C) {                                                           \
        const float v0 = racc0 + __shfl_xor(racc0, 32);                       \
        const float v1 = racc1 + __shfl_xor(racc1, 32);                       \
        if (lhi == 0) {                                                       \
            atomicAdd(&out_t[(size_t)(C) * B_Q + q00 + l31], v0);             \
            atomicAdd(&out_t[(size_t)(C) * B_Q + q01 + l31], v1);             \
        }                                                                     \
    }

__global__ __launch_bounds__(256, 3)
void class_gemm6(const f16* __restrict__ kf2, const f16* __restrict__ qf2,
                 const int* __restrict__ meta, float* __restrict__ out_t) {
    const int tid  = threadIdx.x;
    const int w    = tid >> 6;
    const int lane = tid & 63;
    const int l31  = lane & 31;
    const int lhi  = lane >> 5;
    const int lhi4 = lhi << 2;

    // XCD co-location: 4 qquad-siblings of a chunk share blockIdx%8.
    const int b     = blockIdx.x;
    const int xcd   = b & 7;
    const int s     = b >> 3;               // 0..99
    const int chunk = xcd * (NCHUNK / 8) + (s >> 2);
    const int qquad = s & 3;
    const int g0    = chunk * GPC;

    // Q fragments (B operand): wave w owns queries qquad*256 + w*64 + {0..63}
    f16x8 Q0[8], Q1[8];
    {
        const f16* qa = qf2 + (size_t)(qquad * 8 + w * 2) * 4096 + lane * 8;
        #pragma unroll
        for (int kk = 0; kk < 8; ++kk) {
            Q0[kk] = *(const f16x8*)(qa + kk * 512);
            Q1[kk] = *(const f16x8*)(qa + 4096 + kk * 512);
        }
    }
    const int q00 = qquad * 256 + w * 64;
    const int q01 = q00 + 32;

    // 16 group metas via lanes (no in-loop global latency)
    const int mv = meta[g0 + (lane & 15)];

    float racc0 = 0.0f, racc1 = 0.0f;
    int cur = -1;

    for (int i = 0; i < GPC; ++i) {
        const int m     = __shfl(mv, i);    // wave-uniform
        const int ca    = m & 0x7FF;
        const int cb    = (m >> 11) & 0x7FF;
        const int split = m >> 22;

        // K fragments (A operand) streamed from global, used by both subtiles
        const f16* base = kf2 + (size_t)(g0 + i) * 4096 + lane * 8;
        f32x16 c0 = {}, c1 = {};
        #pragma unroll
        for (int kk = 0; kk < 8; ++kk) {
            const f16x8 Kf = *(const f16x8*)(base + kk * 512);
            c0 = __builtin_amdgcn_mfma_f32_32x32x16_f16(Kf, Q0[kk], c0, 0, 0, 0);
            c1 = __builtin_amdgcn_mfma_f32_32x32x16_f16(Kf, Q1[kk], c1, 0, 0, 0);
        }

        if (ca != cur) {                    // wave-uniform class change
            if (cur >= 0) FLUSH2(cur);
            racc0 = 0.0f; racc1 = 0.0f;
            cur = ca;
        }
        if (split == 32) {                  // common path: whole group one class
            float ga = 0.0f, gb = 0.0f, gc = 0.0f, gd = 0.0f;
            #pragma unroll
            for (int r = 0; r < 16; r += 2) {
                ga += __builtin_amdgcn_exp2f(c0[r]);
                gb += __builtin_amdgcn_exp2f(c0[r + 1]);
                gc += __builtin_amdgcn_exp2f(c1[r]);
                gd += __builtin_amdgcn_exp2f(c1[r + 1]);
            }
            racc0 += ga + gb;
            racc1 += gc + gd;
        } else {                            // boundary group: 2 runs, in-lane split
            float ga = 0.0f, gb = 0.0f, gc = 0.0f, gd = 0.0f;
            float ha = 0.0f, hb = 0.0f, hc = 0.0f, hd = 0.0f;
            #pragma unroll
            for (int r = 0; r < 16; r += 2) {
                // row r holds key (r&3) + 8*(r>>2) + 4*lhi
                const int  kr0 = ((r & 3) + 8 * (r >> 2)) + lhi4;
                const int  kr1 = (((r + 1) & 3) + 8 * ((r + 1) >> 2)) + lhi4;
                const float e0  = __builtin_amdgcn_exp2f(c0[r]);
                const float e0b = __builtin_amdgcn_exp2f(c0[r + 1]);
                const float e1  = __builtin_amdgcn_exp2f(c1[r]);
                const float e1b = __builtin_amdgcn_exp2f(c1[r + 1]);
                const bool inA0 = kr0 < split;
                const bool inA1 = kr1 < split;
                ga += inA0 ? e0  : 0.0f;  ha += inA0 ? 0.0f : e0;
                gb += inA1 ? e0b : 0.0f;  hb += inA1 ? 0.0f : e0b;
                gc += inA0 ? e1  : 0.0f;  hc += inA0 ? 0.0f : e1;
                gd += inA1 ? e1b : 0.0f;  hd += inA1 ? 0.0f : e1b;
            }
            racc0 += ga + gb;
            racc1 += gc + gd;
            FLUSH2(cur);
            racc0 = ha + hb;
            racc1 = hc + hd;
            cur = cb;
        }
    }
    if (cur >= 0) FLUSH2(cur);
}

// ---- epilogue 1: partial class-sums per query (100 blocks x 1024 thr) ----
__global__ __launch_bounds__(1024)
void k_qsum(const float* __restrict__ out_t, float* __restrict__ partial) {
    const int cb = blockIdx.x;
    const int q  = threadIdx.x;
    const float* p = out_t + (size_t)cb * CSUM * B_Q + q;
    float s = 0.0f;
    #pragma unroll
    for (int i = 0; i < CSUM; ++i) s += p[(size_t)i * B_Q];
    partial[cb * B_Q + q] = s;
}

// ---- epilogue 2: 64x64 scaled transpose tiles ----
__global__ __launch_bounds__(256)
void k_norm_t(const float* __restrict__ out_t, const float* __restrict__ partial,
              float* __restrict__ out) {
    __shared__ float tile[64 * 65];
    __shared__ float invq[64];
    const int tid  = threadIdx.x;
    const int w    = tid >> 6;
    const int lane = tid & 63;
    const int q0   = blockIdx.x * 64;
    const int c0   = blockIdx.y * 64;

    if (tid < 64) {
        float s = 0.0f;
        for (int cb = 0; cb < NCB; ++cb) s += partial[cb * B_Q + q0 + tid];
        invq[tid] = 1.0f / s;
    }
    #pragma unroll
    for (int i = 0; i < 16; ++i) {
        const int cidx = c0 + w * 16 + i;
        const float v = (cidx < N_CLS) ? out_t[(size_t)cidx * B_Q + q0 + lane] : 0.0f;
        tile[lane * 65 + w * 16 + i] = v;
    }
    __syncthreads();
    #pragma unroll
    for (int j = 0; j < 16; ++j) {
        const int r    = w * 16 + j;
        const int cidx = c0 + lane;
        if (cidx < N_CLS)
            out[(size_t)(q0 + r) * N_CLS + cidx] = tile[r * 65 + lane] * invq[r];
    }
}

extern "C" void kernel_launch(void* const* d_in, const int* in_sizes, int n_in,
                              void* d_out, int out_size, void* d_ws, size_t ws_size,
                              hipStream_t stream) {
    const float* qm     = (const float*)d_in[0];
    const float* km     = (const float*)d_in[1];
    const int*   labels = (const int*)d_in[2];
    float* out = (float*)d_out;

    char* p = (char*)d_ws;
    f16*   kf2     = (f16*)p;   p += (size_t)NPAD * DIM * 2;        // 26.2 MB
    f16*   qf2     = (f16*)p;   p += (size_t)B_Q * DIM * 2;         // 256 KB
    float* out_t   = (float*)p; p += (size_t)N_CLS * B_Q * 4;       // 4.1 MB
    // NOTE: class-1000 (dummy) bucket row == out_t + 1000*B_Q == partial base.
    // class_gemm6's dummy atomics land there; k_qsum overwrites it afterwards.
    float* partial = (float*)p; p += (size_t)NCB * B_Q * 4;         // 400 KB
    uint*  ghist   = (uint*)p;  p += N_CLS * 4;
    uint*  cursor  = (uint*)p;  p += N_CLS * 4;
    u16*   kcls    = (u16*)p;   p += (size_t)NPAD * 2;              // 205 KB
    int*   meta    = (int*)p;   p += (size_t)NGP * 4;               // 12.8 KB

    hipMemsetAsync(ghist, 0, N_CLS * sizeof(uint), stream);
    hipMemsetAsync(out_t, 0, (size_t)N_CLS * B_Q * sizeof(float), stream);

    hipLaunchKernelGGL(k_hist, dim3(128), dim3(256), 0, stream, labels, ghist);
    hipLaunchKernelGGL(k_scan, dim3(1), dim3(1024), 0, stream, ghist, cursor);

    const int prows = NPAD + B_Q;                  // keys + dummies + queries
    hipLaunchKernelGGL(k_prep, dim3((prows * 64 + 255) / 256), dim3(256), 0, stream,
                       qm, km, labels, cursor, kf2, qf2, kcls);
    hipLaunchKernelGGL(k_meta, dim3((NGP * 64 + 255) / 256), dim3(256), 0, stream,
                       kcls, meta);

    hipLaunchKernelGGL(class_gemm6, dim3(4 * NCHUNK), dim3(256), 0, stream,
                       kf2, qf2, meta, out_t);

    hipLaunchKernelGGL(k_qsum, dim3(NCB), dim3(1024), 0, stream, out_t, partial);
    hipLaunchKernelGGL(k_norm_t, dim3(B_Q / 64, (N_CLS + 63) / 64), dim3(256), 0, stream,
                       out_t, partial, out);
}

// Round 12
// 114.078 us; speedup vs baseline: 2.1066x; 1.0953x over previous
//
#include <hip/hip_runtime.h>
#include <math.h>

typedef _Float16 f16;
typedef _Float16 f16x8 __attribute__((ext_vector_type(8)));
typedef float    f32x16 __attribute__((ext_vector_type(16)));
typedef unsigned int uint;
typedef unsigned short u16;

#define B_Q     1024
#define DIM     128
#define N_KEYS  100000
#define NPAD    102400          /* padded to 3200 groups of 32 */
#define NGP     (NPAD / 32)     /* 3200 groups */
#define GPC     8               /* groups per chunk (256 keys) */
#define NCHUNK  (NGP / GPC)     /* 400 chunks, 50 per XCD */
#define N_CLS   1000
#define QSCALE  11.541560327111707f /* 8/ln2: fold beta*log2(e) into queries */
#define CSUM    10
#define NCB     (N_CLS / CSUM)  /* 100 */
#define NH      128             /* hist blocks */

// ---- label histogram: per-block rows, no global atomics ----
__global__ void k_hist(const int* __restrict__ labels, uint* __restrict__ hist128) {
    __shared__ uint lh[N_CLS];
    for (int i = threadIdx.x; i < N_CLS; i += blockDim.x) lh[i] = 0;
    __syncthreads();
    const int stride = gridDim.x * blockDim.x;
    for (int i = blockIdx.x * blockDim.x + threadIdx.x; i < N_KEYS; i += stride)
        atomicAdd(&lh[labels[i]], 1u);
    __syncthreads();
    for (int i = threadIdx.x; i < N_CLS; i += blockDim.x)
        hist128[blockIdx.x * N_CLS + i] = lh[i];
}

// ---- reduce per-block hists + exclusive scan -> cursor ----
__global__ void k_scan(const uint* __restrict__ hist128, uint* __restrict__ cursor) {
    __shared__ uint s[1024];
    const int t = threadIdx.x;
    uint v = 0;
    if (t < N_CLS)
        for (int b = 0; b < NH; ++b) v += hist128[b * N_CLS + t];
    s[t] = v; __syncthreads();
    for (int o = 1; o < 1024; o <<= 1) {
        const uint x = (t >= o) ? s[t - o] : 0u;
        __syncthreads();
        s[t] += x;
        __syncthreads();
    }
    if (t < N_CLS) cursor[t] = s[t] - v;
}

// ---- fused prep: normalize, f16, scatter into MFMA-fragment order; dummies ----
// layout per 32-row group: [kk(8)][lane(64)][j(8)] f16; (kk,lane,j) =
// row (lane&31), dim kk*16 + (lane>>5)*8 + j. (A/B operand layouts are
// lane-symmetric, so the same layout serves K-as-A and Q-as-B.)
__global__ void k_prep(const float* __restrict__ qm, const float* __restrict__ km,
                       const int* __restrict__ labels, uint* __restrict__ cursor,
                       f16* __restrict__ kf2, f16* __restrict__ qf2,
                       u16* __restrict__ kcls) {
    const int gid  = blockIdx.x * blockDim.x + threadIdx.x;
    const int n    = gid >> 6;
    const int lane = threadIdx.x & 63;
    if (n >= NPAD + B_Q) return;
    const bool isq   = n >= NPAD;
    const bool dummy = !isq && n >= N_KEYS;

    float a = 0.0f, b = 0.0f;
    if (!dummy) {
        const float* row = isq ? qm + (size_t)(n - NPAD) * DIM
                               : km + (size_t)n * DIM;
        a = row[lane]; b = row[lane + 64];
    }
    float ss = a * a + b * b;
    #pragma unroll
    for (int o = 32; o >= 1; o >>= 1) ss += __shfl_xor(ss, o);
    const float rn = (isq ? QSCALE : 1.0f) / fmaxf(sqrtf(ss), 1e-12f);

    int pos;
    if (isq)        pos = n - NPAD;
    else if (dummy) { pos = n; if (lane == 0) kcls[pos] = (u16)N_CLS; }
    else {
        const int lab = labels[n];
        if (lane == 0) pos = (int)atomicAdd(&cursor[lab], 1u);
        pos = __shfl(pos, 0);
        if (lane == 0) kcls[pos] = (u16)lab;
    }

    const float va = a * rn, vb = b * rn;   // dummy rows stay exactly 0
    f16x8 hv;
    #pragma unroll
    for (int j = 0; j < 8; ++j) {
        const int src = (lane & 15) * 8 + j;        // 0..127
        const float xa = __shfl(va, src & 63);
        const float xb = __shfl(vb, src & 63);
        hv[j] = (f16)((src < 64) ? xa : xb);
    }
    if (lane < 16) {
        f16* dst = isq ? qf2 : kf2;
        const int kk  = lane >> 1;
        const int lhi = lane & 1;
        *(f16x8*)(dst + (size_t)(pos >> 5) * 4096 + kk * 512 +
                  ((lhi << 5) + (pos & 31)) * 8) = hv;
    }
}

// ---- per-group class metadata (+ fused out_t zeroing, saves a memset) ----
__global__ void k_meta(const u16* __restrict__ kcls, int* __restrict__ meta,
                       float* __restrict__ out_t) {
    // zero out_t: grid-stride float4 over 800 blocks x 256 threads
    const int nt = gridDim.x * blockDim.x;
    const float4 z = {0.0f, 0.0f, 0.0f, 0.0f};
    for (int i = blockIdx.x * blockDim.x + threadIdx.x;
         i < N_CLS * B_Q / 4; i += nt)
        ((float4*)out_t)[i] = z;

    const int gid  = blockIdx.x * blockDim.x + threadIdx.x;
    const int g    = gid >> 6;
    const int lane = threadIdx.x & 63;
    if (g >= NGP) return;
    const int  cl = kcls[g * 32 + (lane & 31)];
    const int  ca = __shfl(cl, 0);
    const uint dm = (uint)(__ballot(cl != ca) & 0xffffffffull);
    const int  split = dm ? (__ffs(dm) - 1) : 32;
    const int  cb = (split < 32) ? __shfl(cl, split) : ca;
    if (lane == 0) meta[g] = ca | (cb << 11) | (split << 22);
}

// ---- main: SWAPPED-OPERAND MFMA. D = K_frag x Q_frag -> D[key][q]:
// col = lane&31 = QUERY (lane-local), rows = keys. Segment-sum over keys is
// per-lane scalar adds; flush = 1 shfl_xor(32) + 1 atomicAdd per subtile.
// Barrier-free, LDS-free; 3200 blocks x 4 independent waves (GPC=8: r11's
// 800-block grid held occupancy at 17.6% -> 4x blocks for TLP); keys
// streamed from global (fragment-ordered, coalesced); XCD co-located chunks.
#define FLUSH2(C) {                                                           \
        const float v0 = racc0 + __shfl_xor(racc0, 32);                       \
        const float v1 = racc1 + __shfl_xor(racc1, 32);                       \
        if (lhi == 0) {                                                       \
            atomicAdd(&out_t[(size_t)(C) * B_Q + q00 + l31], v0);             \
            atomicAdd(&out_t[(size_t)(C) * B_Q + q01 + l31], v1);             \
        }                                                                     \
    }

__global__ __launch_bounds__(256, 3)
void class_gemm6(const f16* __restrict__ kf2, const f16* __restrict__ qf2,
                 const int* __restrict__ meta, float* __restrict__ out_t) {
    const int tid  = threadIdx.x;
    const int w    = tid >> 6;
    const int lane = tid & 63;
    const int l31  = lane & 31;
    const int lhi  = lane >> 5;
    const int lhi4 = lhi << 2;

    // XCD co-location: 4 qquad-siblings of a chunk share blockIdx%8.
    const int b     = blockIdx.x;
    const int xcd   = b & 7;
    const int s     = b >> 3;               // 0..399
    const int chunk = xcd * (NCHUNK / 8) + (s >> 2);
    const int qquad = s & 3;
    const int g0    = chunk * GPC;

    // Q fragments (B operand): wave w owns queries qquad*256 + w*64 + {0..63}
    f16x8 Q0[8], Q1[8];
    {
        const f16* qa = qf2 + (size_t)(qquad * 8 + w * 2) * 4096 + lane * 8;
        #pragma unroll
        for (int kk = 0; kk < 8; ++kk) {
            Q0[kk] = *(const f16x8*)(qa + kk * 512);
            Q1[kk] = *(const f16x8*)(qa + 4096 + kk * 512);
        }
    }
    const int q00 = qquad * 256 + w * 64;
    const int q01 = q00 + 32;

    // GPC group metas via lanes (no in-loop global latency)
    const int mv = meta[g0 + (lane & (GPC - 1))];

    float racc0 = 0.0f, racc1 = 0.0f;
    int cur = -1;

    for (int i = 0; i < GPC; ++i) {
        const int m     = __shfl(mv, i);    // wave-uniform
        const int ca    = m & 0x7FF;
        const int cb    = (m >> 11) & 0x7FF;
        const int split = m >> 22;

        // K fragments (A operand) streamed from global, used by both subtiles
        const f16* base = kf2 + (size_t)(g0 + i) * 4096 + lane * 8;
        f32x16 c0 = {}, c1 = {};
        #pragma unroll
        for (int kk = 0; kk < 8; ++kk) {
            const f16x8 Kf = *(const f16x8*)(base + kk * 512);
            c0 = __builtin_amdgcn_mfma_f32_32x32x16_f16(Kf, Q0[kk], c0, 0, 0, 0);
            c1 = __builtin_amdgcn_mfma_f32_32x32x16_f16(Kf, Q1[kk], c1, 0, 0, 0);
        }

        if (ca != cur) {                    // wave-uniform class change
            if (cur >= 0) FLUSH2(cur);
            racc0 = 0.0f; racc1 = 0.0f;
            cur = ca;
        }
        if (split == 32) {                  // common path: whole group one class
            float ga = 0.0f, gb = 0.0f, gc = 0.0f, gd = 0.0f;
            #pragma unroll
            for (int r = 0; r < 16; r += 2) {
                ga += __builtin_amdgcn_exp2f(c0[r]);
                gb += __builtin_amdgcn_exp2f(c0[r + 1]);
                gc += __builtin_amdgcn_exp2f(c1[r]);
                gd += __builtin_amdgcn_exp2f(c1[r + 1]);
            }
            racc0 += ga + gb;
            racc1 += gc + gd;
        } else {                            // boundary group: 2 runs, in-lane split
            float ga = 0.0f, gb = 0.0f, gc = 0.0f, gd = 0.0f;
            float ha = 0.0f, hb = 0.0f, hc = 0.0f, hd = 0.0f;
            #pragma unroll
            for (int r = 0; r < 16; r += 2) {
                // row r holds key (r&3) + 8*(r>>2) + 4*lhi
                const int  kr0 = ((r & 3) + 8 * (r >> 2)) + lhi4;
                const int  kr1 = (((r + 1) & 3) + 8 * ((r + 1) >> 2)) + lhi4;
                const float e0  = __builtin_amdgcn_exp2f(c0[r]);
                const float e0b = __builtin_amdgcn_exp2f(c0[r + 1]);
                const float e1  = __builtin_amdgcn_exp2f(c1[r]);
                const float e1b = __builtin_amdgcn_exp2f(c1[r + 1]);
                const bool inA0 = kr0 < split;
                const bool inA1 = kr1 < split;
                ga += inA0 ? e0  : 0.0f;  ha += inA0 ? 0.0f : e0;
                gb += inA1 ? e0b : 0.0f;  hb += inA1 ? 0.0f : e0b;
                gc += inA0 ? e1  : 0.0f;  hc += inA0 ? 0.0f : e1;
                gd += inA1 ? e1b : 0.0f;  hd += inA1 ? 0.0f : e1b;
            }
            racc0 += ga + gb;
            racc1 += gc + gd;
            FLUSH2(cur);
            racc0 = ha + hb;
            racc1 = hc + hd;
            cur = cb;
        }
    }
    if (cur >= 0) FLUSH2(cur);
}

// ---- epilogue 1: partial class-sums per query (100 blocks x 1024 thr) ----
__global__ __launch_bounds__(1024)
void k_qsum(const float* __restrict__ out_t, float* __restrict__ partial) {
    const int cb = blockIdx.x;
    const int q  = threadIdx.x;
    const float* p = out_t + (size_t)cb * CSUM * B_Q + q;
    float s = 0.0f;
    #pragma unroll
    for (int i = 0; i < CSUM; ++i) s += p[(size_t)i * B_Q];
    partial[cb * B_Q + q] = s;
}

// ---- epilogue 2: 64x64 scaled transpose tiles ----
__global__ __launch_bounds__(256)
void k_norm_t(const float* __restrict__ out_t, const float* __restrict__ partial,
              float* __restrict__ out) {
    __shared__ float tile[64 * 65];
    __shared__ float invq[64];
    const int tid  = threadIdx.x;
    const int w    = tid >> 6;
    const int lane = tid & 63;
    const int q0   = blockIdx.x * 64;
    const int c0   = blockIdx.y * 64;

    if (tid < 64) {
        float s = 0.0f;
        for (int cb = 0; cb < NCB; ++cb) s += partial[cb * B_Q + q0 + tid];
        invq[tid] = 1.0f / s;
    }
    #pragma unroll
    for (int i = 0; i < 16; ++i) {
        const int cidx = c0 + w * 16 + i;
        const float v = (cidx < N_CLS) ? out_t[(size_t)cidx * B_Q + q0 + lane] : 0.0f;
        tile[lane * 65 + w * 16 + i] = v;
    }
    __syncthreads();
    #pragma unroll
    for (int j = 0; j < 16; ++j) {
        const int r    = w * 16 + j;
        const int cidx = c0 + lane;
        if (cidx < N_CLS)
            out[(size_t)(q0 + r) * N_CLS + cidx] = tile[r * 65 + lane] * invq[r];
    }
}

extern "C" void kernel_launch(void* const* d_in, const int* in_sizes, int n_in,
                              void* d_out, int out_size, void* d_ws, size_t ws_size,
                              hipStream_t stream) {
    const float* qm     = (const float*)d_in[0];
    const float* km     = (const float*)d_in[1];
    const int*   labels = (const int*)d_in[2];
    float* out = (float*)d_out;

    char* p = (char*)d_ws;
    f16*   kf2     = (f16*)p;   p += (size_t)NPAD * DIM * 2;        // 26.2 MB
    f16*   qf2     = (f16*)p;   p += (size_t)B_Q * DIM * 2;         // 256 KB
    float* out_t   = (float*)p; p += (size_t)N_CLS * B_Q * 4;       // 4.1 MB
    // NOTE: class-1000 (dummy) bucket row == out_t + 1000*B_Q == partial base.
    // class_gemm6's dummy atomics land there; k_qsum overwrites it afterwards.
    float* partial = (float*)p; p += (size_t)NCB * B_Q * 4;         // 400 KB
    uint*  cursor  = (uint*)p;  p += N_CLS * 4;
    u16*   kcls    = (u16*)p;   p += (size_t)NPAD * 2;              // 205 KB
    int*   meta    = (int*)p;   p += (size_t)NGP * 4;               // 12.8 KB
    // hist128 aliases the out_t region: written by k_hist, consumed by k_scan,
    // then k_meta zeroes out_t (strictly after, stream-ordered).
    uint*  hist128 = (uint*)out_t;                                  // 512 KB

    hipLaunchKernelGGL(k_hist, dim3(NH), dim3(256), 0, stream, labels, hist128);
    hipLaunchKernelGGL(k_scan, dim3(1), dim3(1024), 0, stream, hist128, cursor);

    const int prows = NPAD + B_Q;                  // keys + dummies + queries
    hipLaunchKernelGGL(k_prep, dim3((prows * 64 + 255) / 256), dim3(256), 0, stream,
                       qm, km, labels, cursor, kf2, qf2, kcls);
    hipLaunchKernelGGL(k_meta, dim3((NGP * 64 + 255) / 256), dim3(256), 0, stream,
                       kcls, meta, out_t);

    hipLaunchKernelGGL(class_gemm6, dim3(4 * NCHUNK), dim3(256), 0, stream,
                       kf2, qf2, meta, out_t);

    hipLaunchKernelGGL(k_qsum, dim3(NCB), dim3(1024), 0, stream, out_t, partial);
    hipLaunchKernelGGL(k_norm_t, dim3(B_Q / 64, (N_CLS + 63) / 64), dim3(256), 0, stream,
                       out_t, partial, out);
}

// Round 13
// 110.657 us; speedup vs baseline: 2.1717x; 1.0309x over previous
//
#include <hip/hip_runtime.h>
#include <math.h>

typedef _Float16 f16;
typedef _Float16 f16x8 __attribute__((ext_vector_type(8)));
typedef float    f32x16 __attribute__((ext_vector_type(16)));
typedef unsigned int uint;
typedef unsigned short u16;

#define B_Q     1024
#define DIM     128
#define N_KEYS  100000
#define NPAD    102400          /* padded to 3200 groups of 32 */
#define NGP     (NPAD / 32)     /* 3200 groups */
#define GPC     8               /* groups per chunk (256 keys) */
#define NCHUNK  (NGP / GPC)     /* 400 chunks, 50 per XCD */
#define N_CLS   1000
#define QSCALE  11.541560327111707f /* 8/ln2: fold beta*log2(e) into queries */
#define CSUM    10
#define NCB     (N_CLS / CSUM)  /* 100 */
#define NH      128             /* hist blocks */
#define QGRP    (B_Q / 32)      /* 32 query groups */

// ---- label histogram: per-block rows, no global atomics ----
__global__ void k_hist(const int* __restrict__ labels, uint* __restrict__ hist128) {
    __shared__ uint lh[N_CLS];
    for (int i = threadIdx.x; i < N_CLS; i += blockDim.x) lh[i] = 0;
    __syncthreads();
    const int stride = gridDim.x * blockDim.x;
    for (int i = blockIdx.x * blockDim.x + threadIdx.x; i < N_KEYS; i += stride)
        atomicAdd(&lh[labels[i]], 1u);
    __syncthreads();
    for (int i = threadIdx.x; i < N_CLS; i += blockDim.x)
        hist128[blockIdx.x * N_CLS + i] = lh[i];
}

// ---- reduce per-block hists + exclusive scan -> cursor ----
__global__ void k_scan(const uint* __restrict__ hist128, uint* __restrict__ cursor) {
    __shared__ uint s[1024];
    const int t = threadIdx.x;
    uint v = 0;
    if (t < N_CLS)
        for (int b = 0; b < NH; ++b) v += hist128[b * N_CLS + t];
    s[t] = v; __syncthreads();
    for (int o = 1; o < 1024; o <<= 1) {
        const uint x = (t >= o) ? s[t - o] : 0u;
        __syncthreads();
        s[t] += x;
        __syncthreads();
    }
    if (t < N_CLS) cursor[t] = s[t] - v;
}

// ---- sort permutation: src[pos] = source key index; dummies src = -1 ----
__global__ void k_perm(const int* __restrict__ labels, uint* __restrict__ cursor,
                       int* __restrict__ src, u16* __restrict__ kcls) {
    const int n = blockIdx.x * blockDim.x + threadIdx.x;
    if (n >= NPAD) return;
    if (n < N_KEYS) {
        const int lab = labels[n];
        const int pos = (int)atomicAdd(&cursor[lab], 1u);
        src[pos]  = n;
        kcls[pos] = (u16)lab;
    } else {                       // dummy rows occupy positions N_KEYS..NPAD-1
        src[n]  = -1;
        kcls[n] = (u16)N_CLS;
    }
}

// ---- gather-prep: block = one 32-row destination group; shuffle-free.
// Thread (r=t&31, p=t>>5) reads 64B of source row, LDS ssq reduce, writes
// 16 f16 in fragment order as two coalesced 16B stores.
// Fragment layout per group: [kk(8)][lane(64)][j(8)]; (kk,lane,j) =
// row lane&31, dim kk*16 + (lane>>5)*8 + j.
__global__ __launch_bounds__(256)
void k_gather(const float* __restrict__ qm, const float* __restrict__ km,
              const int* __restrict__ src, f16* __restrict__ kf2,
              f16* __restrict__ qf2) {
    __shared__ float ssq[8][32];
    __shared__ float scale[32];
    const int g = blockIdx.x;            // 0..NGP-1 keys, NGP..NGP+31 queries
    const int t = threadIdx.x;
    const int r = t & 31;
    const int p = t >> 5;
    const bool isq = g >= NGP;

    const float* srow;
    if (isq) srow = qm + (size_t)((g - NGP) * 32 + r) * DIM;
    else {
        const int sr = src[g * 32 + r];
        srow = (sr >= 0) ? km + (size_t)sr * DIM : nullptr;
    }

    float4 v[4];
    float ss = 0.0f;
    if (srow) {
        #pragma unroll
        for (int i = 0; i < 4; ++i) {
            v[i] = *(const float4*)(srow + p * 16 + i * 4);
            ss += v[i].x * v[i].x + v[i].y * v[i].y
                + v[i].z * v[i].z + v[i].w * v[i].w;
        }
    } else {
        #pragma unroll
        for (int i = 0; i < 4; ++i) v[i] = float4{0.f, 0.f, 0.f, 0.f};
    }
    ssq[p][r] = ss;
    __syncthreads();
    if (t < 32) {
        float s = 0.0f;
        #pragma unroll
        for (int i = 0; i < 8; ++i) s += ssq[i][t];
        scale[t] = (isq ? QSCALE : 1.0f) / fmaxf(sqrtf(s), 1e-12f);
    }
    __syncthreads();
    const float sc = scale[r];

    const float f[16] = {v[0].x, v[0].y, v[0].z, v[0].w,
                         v[1].x, v[1].y, v[1].z, v[1].w,
                         v[2].x, v[2].y, v[2].z, v[2].w,
                         v[3].x, v[3].y, v[3].z, v[3].w};
    f16x8 h0, h1;
    #pragma unroll
    for (int j = 0; j < 8; ++j) {
        h0[j] = (f16)(f[j]     * sc);
        h1[j] = (f16)(f[j + 8] * sc);
    }
    f16* dst = isq ? qf2 + (size_t)(g - NGP) * 4096
                   : kf2 + (size_t)g * 4096;
    *(f16x8*)(dst + p * 512 +       r * 8) = h0;   // lhi=0 slots
    *(f16x8*)(dst + p * 512 + 256 + r * 8) = h1;   // lhi=1 slots
}

// ---- per-group class metadata (+ fused out_t zeroing, saves a memset) ----
__global__ void k_meta(const u16* __restrict__ kcls, int* __restrict__ meta,
                       float* __restrict__ out_t) {
    const int nt = gridDim.x * blockDim.x;
    const float4 z = {0.0f, 0.0f, 0.0f, 0.0f};
    for (int i = blockIdx.x * blockDim.x + threadIdx.x;
         i < N_CLS * B_Q / 4; i += nt)
        ((float4*)out_t)[i] = z;

    const int gid  = blockIdx.x * blockDim.x + threadIdx.x;
    const int g    = gid >> 6;
    const int lane = threadIdx.x & 63;
    if (g >= NGP) return;
    const int  cl = kcls[g * 32 + (lane & 31)];
    const int  ca = __shfl(cl, 0);
    const uint dm = (uint)(__ballot(cl != ca) & 0xffffffffull);
    const int  split = dm ? (__ffs(dm) - 1) : 32;
    const int  cb = (split < 32) ? __shfl(cl, split) : ca;
    if (lane == 0) meta[g] = ca | (cb << 11) | (split << 22);
}

// ---- main: SWAPPED-OPERAND MFMA. D = K_frag x Q_frag -> D[key][q]:
// col = lane&31 = QUERY (lane-local), rows = keys. Segment-sum over keys is
// per-lane scalar adds; flush = 1 shfl_xor(32) + 1 atomicAdd per subtile.
// Barrier-free, LDS-free; 3200 blocks x 4 independent waves; keys streamed
// from global (fragment-ordered, coalesced); XCD co-located chunks.
#define FLUSH2(C) {                                                           \
        const float v0 = racc0 + __shfl_xor(racc0, 32);                       \
        const float v1 = racc1 + __shfl_xor(racc1, 32);                       \
        if (lhi == 0) {                                                       \
            atomicAdd(&out_t[(size_t)(C) * B_Q + q00 + l31], v0);             \
            atomicAdd(&out_t[(size_t)(C) * B_Q + q01 + l31], v1);             \
        }                                                                     \
    }

__global__ __launch_bounds__(256, 3)
void class_gemm6(const f16* __restrict__ kf2, const f16* __restrict__ qf2,
                 const int* __restrict__ meta, float* __restrict__ out_t) {
    const int tid  = threadIdx.x;
    const int w    = tid >> 6;
    const int lane = tid & 63;
    const int l31  = lane & 31;
    const int lhi  = lane >> 5;
    const int lhi4 = lhi << 2;

    const int b     = blockIdx.x;
    const int xcd   = b & 7;
    const int s     = b >> 3;               // 0..399
    const int chunk = xcd * (NCHUNK / 8) + (s >> 2);
    const int qquad = s & 3;
    const int g0    = chunk * GPC;

    f16x8 Q0[8], Q1[8];
    {
        const f16* qa = qf2 + (size_t)(qquad * 8 + w * 2) * 4096 + lane * 8;
        #pragma unroll
        for (int kk = 0; kk < 8; ++kk) {
            Q0[kk] = *(const f16x8*)(qa + kk * 512);
            Q1[kk] = *(const f16x8*)(qa + 4096 + kk * 512);
        }
    }
    const int q00 = qquad * 256 + w * 64;
    const int q01 = q00 + 32;

    const int mv = meta[g0 + (lane & (GPC - 1))];

    float racc0 = 0.0f, racc1 = 0.0f;
    int cur = -1;

    for (int i = 0; i < GPC; ++i) {
        const int m     = __shfl(mv, i);    // wave-uniform
        const int ca    = m & 0x7FF;
        const int cb    = (m >> 11) & 0x7FF;
        const int split = m >> 22;

        const f16* base = kf2 + (size_t)(g0 + i) * 4096 + lane * 8;
        f32x16 c0 = {}, c1 = {};
        #pragma unroll
        for (int kk = 0; kk < 8; ++kk) {
            const f16x8 Kf = *(const f16x8*)(base + kk * 512);
            c0 = __builtin_amdgcn_mfma_f32_32x32x16_f16(Kf, Q0[kk], c0, 0, 0, 0);
            c1 = __builtin_amdgcn_mfma_f32_32x32x16_f16(Kf, Q1[kk], c1, 0, 0, 0);
        }

        if (ca != cur) {                    // wave-uniform class change
            if (cur >= 0) FLUSH2(cur);
            racc0 = 0.0f; racc1 = 0.0f;
            cur = ca;
        }
        if (split == 32) {                  // common path: whole group one class
            float ga = 0.0f, gb = 0.0f, gc = 0.0f, gd = 0.0f;
            #pragma unroll
            for (int r = 0; r < 16; r += 2) {
                ga += __builtin_amdgcn_exp2f(c0[r]);
                gb += __builtin_amdgcn_exp2f(c0[r + 1]);
                gc += __builtin_amdgcn_exp2f(c1[r]);
                gd += __builtin_amdgcn_exp2f(c1[r + 1]);
            }
            racc0 += ga + gb;
            racc1 += gc + gd;
        } else {                            // boundary group: 2 runs, in-lane split
            float ga = 0.0f, gb = 0.0f, gc = 0.0f, gd = 0.0f;
            float ha = 0.0f, hb = 0.0f, hc = 0.0f, hd = 0.0f;
            #pragma unroll
            for (int r = 0; r < 16; r += 2) {
                const int  kr0 = ((r & 3) + 8 * (r >> 2)) + lhi4;
                const int  kr1 = (((r + 1) & 3) + 8 * ((r + 1) >> 2)) + lhi4;
                const float e0  = __builtin_amdgcn_exp2f(c0[r]);
                const float e0b = __builtin_amdgcn_exp2f(c0[r + 1]);
                const float e1  = __builtin_amdgcn_exp2f(c1[r]);
                const float e1b = __builtin_amdgcn_exp2f(c1[r + 1]);
                const bool inA0 = kr0 < split;
                const bool inA1 = kr1 < split;
                ga += inA0 ? e0  : 0.0f;  ha += inA0 ? 0.0f : e0;
                gb += inA1 ? e0b : 0.0f;  hb += inA1 ? 0.0f : e0b;
                gc += inA0 ? e1  : 0.0f;  hc += inA0 ? 0.0f : e1;
                gd += inA1 ? e1b : 0.0f;  hd += inA1 ? 0.0f : e1b;
            }
            racc0 += ga + gb;
            racc1 += gc + gd;
            FLUSH2(cur);
            racc0 = ha + hb;
            racc1 = hc + hd;
            cur = cb;
        }
    }
    if (cur >= 0) FLUSH2(cur);
}

// ---- epilogue 1: partial class-sums per query (100 blocks x 1024 thr) ----
__global__ __launch_bounds__(1024)
void k_qsum(const float* __restrict__ out_t, float* __restrict__ partial) {
    const int cb = blockIdx.x;
    const int q  = threadIdx.x;
    const float* p = out_t + (size_t)cb * CSUM * B_Q + q;
    float s = 0.0f;
    #pragma unroll
    for (int i = 0; i < CSUM; ++i) s += p[(size_t)i * B_Q];
    partial[cb * B_Q + q] = s;
}

// ---- epilogue 2: 64x64 scaled transpose tiles ----
__global__ __launch_bounds__(256)
void k_norm_t(const float* __restrict__ out_t, const float* __restrict__ partial,
              float* __restrict__ out) {
    __shared__ float tile[64 * 65];
    __shared__ float invq[64];
    const int tid  = threadIdx.x;
    const int w    = tid >> 6;
    const int lane = tid & 63;
    const int q0   = blockIdx.x * 64;
    const int c0   = blockIdx.y * 64;

    if (tid < 64) {
        float s = 0.0f;
        for (int cb = 0; cb < NCB; ++cb) s += partial[cb * B_Q + q0 + tid];
        invq[tid] = 1.0f / s;
    }
    #pragma unroll
    for (int i = 0; i < 16; ++i) {
        const int cidx = c0 + w * 16 + i;
        const float v = (cidx < N_CLS) ? out_t[(size_t)cidx * B_Q + q0 + lane] : 0.0f;
        tile[lane * 65 + w * 16 + i] = v;
    }
    __syncthreads();
    #pragma unroll
    for (int j = 0; j < 16; ++j) {
        const int r    = w * 16 + j;
        const int cidx = c0 + lane;
        if (cidx < N_CLS)
            out[(size_t)(q0 + r) * N_CLS + cidx] = tile[r * 65 + lane] * invq[r];
    }
}

extern "C" void kernel_launch(void* const* d_in, const int* in_sizes, int n_in,
                              void* d_out, int out_size, void* d_ws, size_t ws_size,
                              hipStream_t stream) {
    const float* qm     = (const float*)d_in[0];
    const float* km     = (const float*)d_in[1];
    const int*   labels = (const int*)d_in[2];
    float* out = (float*)d_out;

    char* p = (char*)d_ws;
    f16*   kf2     = (f16*)p;   p += (size_t)NPAD * DIM * 2;        // 26.2 MB
    f16*   qf2     = (f16*)p;   p += (size_t)B_Q * DIM * 2;         // 256 KB
    float* out_t   = (float*)p; p += (size_t)N_CLS * B_Q * 4;       // 4.1 MB
    // NOTE: class-1000 (dummy) bucket row == out_t + 1000*B_Q == partial base.
    // class_gemm6's dummy atomics land there; k_qsum overwrites it afterwards.
    float* partial = (float*)p; p += (size_t)NCB * B_Q * 4;         // 400 KB
    uint*  cursor  = (uint*)p;  p += N_CLS * 4;
    u16*   kcls    = (u16*)p;   p += (size_t)NPAD * 2;              // 205 KB
    int*   meta    = (int*)p;   p += (size_t)NGP * 4;               // 12.8 KB
    int*   src     = (int*)p;   p += (size_t)NPAD * 4;              // 410 KB
    // hist128 aliases the out_t region: written by k_hist, consumed by k_scan,
    // then k_meta zeroes out_t (strictly after, stream-ordered).
    uint*  hist128 = (uint*)out_t;                                  // 512 KB

    hipLaunchKernelGGL(k_hist, dim3(NH), dim3(256), 0, stream, labels, hist128);
    hipLaunchKernelGGL(k_scan, dim3(1), dim3(1024), 0, stream, hist128, cursor);
    hipLaunchKernelGGL(k_perm, dim3(NPAD / 256), dim3(256), 0, stream,
                       labels, cursor, src, kcls);
    hipLaunchKernelGGL(k_gather, dim3(NGP + QGRP), dim3(256), 0, stream,
                       qm, km, src, kf2, qf2);
    hipLaunchKernelGGL(k_meta, dim3((NGP * 64 + 255) / 256), dim3(256), 0, stream,
                       kcls, meta, out_t);

    hipLaunchKernelGGL(class_gemm6, dim3(4 * NCHUNK), dim3(256), 0, stream,
                       kf2, qf2, meta, out_t);

    hipLaunchKernelGGL(k_qsum, dim3(NCB), dim3(1024), 0, stream, out_t, partial);
    hipLaunchKernelGGL(k_norm_t, dim3(B_Q / 64, (N_CLS + 63) / 64), dim3(256), 0, stream,
                       out_t, partial, out);
}

// Round 14
// 101.592 us; speedup vs baseline: 2.3655x; 1.0892x over previous
//
#include <hip/hip_runtime.h>
#include <math.h>

typedef _Float16 f16;
typedef _Float16 f16x8 __attribute__((ext_vector_type(8)));
typedef float    f32x16 __attribute__((ext_vector_type(16)));
typedef unsigned int uint;
typedef unsigned short u16;

#define B_Q     1024
#define DIM     128
#define N_KEYS  100000
#define NPAD    102400          /* padded to 3200 groups of 32 */
#define NGP     (NPAD / 32)     /* 3200 groups */
#define GPC     8               /* groups per chunk (256 keys) */
#define NCHUNK  (NGP / GPC)     /* 400 chunks, 50 per XCD */
#define N_CLS   1000
#define QSCALE  11.541560327111707f /* 8/ln2: fold beta*log2(e) into queries */
#define NH      128             /* hist blocks */
#define QGRP    (B_Q / 32)      /* 32 query groups */

// ---- label histogram: per-block rows, no global atomics ----
__global__ void k_hist(const int* __restrict__ labels, uint* __restrict__ hist128) {
    __shared__ uint lh[N_CLS];
    for (int i = threadIdx.x; i < N_CLS; i += blockDim.x) lh[i] = 0;
    __syncthreads();
    const int stride = gridDim.x * blockDim.x;
    for (int i = blockIdx.x * blockDim.x + threadIdx.x; i < N_KEYS; i += stride)
        atomicAdd(&lh[labels[i]], 1u);
    __syncthreads();
    for (int i = threadIdx.x; i < N_CLS; i += blockDim.x)
        hist128[blockIdx.x * N_CLS + i] = lh[i];
}

// ---- reduce per-block hists + exclusive scan -> cursor ----
__global__ void k_scan(const uint* __restrict__ hist128, uint* __restrict__ cursor) {
    __shared__ uint s[1024];
    const int t = threadIdx.x;
    uint v = 0;
    if (t < N_CLS)
        for (int b = 0; b < NH; ++b) v += hist128[b * N_CLS + t];
    s[t] = v; __syncthreads();
    for (int o = 1; o < 1024; o <<= 1) {
        const uint x = (t >= o) ? s[t - o] : 0u;
        __syncthreads();
        s[t] += x;
        __syncthreads();
    }
    if (t < N_CLS) cursor[t] = s[t] - v;
}

// ---- sort permutation: src[pos] = source key index; dummies src = -1 ----
__global__ void k_perm(const int* __restrict__ labels, uint* __restrict__ cursor,
                       int* __restrict__ src, u16* __restrict__ kcls) {
    const int n = blockIdx.x * blockDim.x + threadIdx.x;
    if (n >= NPAD) return;
    if (n < N_KEYS) {
        const int lab = labels[n];
        const int pos = (int)atomicAdd(&cursor[lab], 1u);
        src[pos]  = n;
        kcls[pos] = (u16)lab;
    } else {
        src[n]  = -1;
        kcls[n] = (u16)N_CLS;
    }
}

// ---- gather-prep: block = one 32-row destination group; shuffle-free ----
__global__ __launch_bounds__(256)
void k_gather(const float* __restrict__ qm, const float* __restrict__ km,
              const int* __restrict__ src, f16* __restrict__ kf2,
              f16* __restrict__ qf2) {
    __shared__ float ssq[8][32];
    __shared__ float scale[32];
    const int g = blockIdx.x;            // 0..NGP-1 keys, NGP..NGP+31 queries
    const int t = threadIdx.x;
    const int r = t & 31;
    const int p = t >> 5;
    const bool isq = g >= NGP;

    const float* srow;
    if (isq) srow = qm + (size_t)((g - NGP) * 32 + r) * DIM;
    else {
        const int sr = src[g * 32 + r];
        srow = (sr >= 0) ? km + (size_t)sr * DIM : nullptr;
    }

    float4 v[4];
    float ss = 0.0f;
    if (srow) {
        #pragma unroll
        for (int i = 0; i < 4; ++i) {
            v[i] = *(const float4*)(srow + p * 16 + i * 4);
            ss += v[i].x * v[i].x + v[i].y * v[i].y
                + v[i].z * v[i].z + v[i].w * v[i].w;
        }
    } else {
        #pragma unroll
        for (int i = 0; i < 4; ++i) v[i] = float4{0.f, 0.f, 0.f, 0.f};
    }
    ssq[p][r] = ss;
    __syncthreads();
    if (t < 32) {
        float s = 0.0f;
        #pragma unroll
        for (int i = 0; i < 8; ++i) s += ssq[i][t];
        scale[t] = (isq ? QSCALE : 1.0f) / fmaxf(sqrtf(s), 1e-12f);
    }
    __syncthreads();
    const float sc = scale[r];

    const float f[16] = {v[0].x, v[0].y, v[0].z, v[0].w,
                         v[1].x, v[1].y, v[1].z, v[1].w,
                         v[2].x, v[2].y, v[2].z, v[2].w,
                         v[3].x, v[3].y, v[3].z, v[3].w};
    f16x8 h0, h1;
    #pragma unroll
    for (int j = 0; j < 8; ++j) {
        h0[j] = (f16)(f[j]     * sc);
        h1[j] = (f16)(f[j + 8] * sc);
    }
    f16* dst = isq ? qf2 + (size_t)(g - NGP) * 4096
                   : kf2 + (size_t)g * 4096;
    *(f16x8*)(dst + p * 512 +       r * 8) = h0;
    *(f16x8*)(dst + p * 512 + 256 + r * 8) = h1;
}

// ---- per-group class metadata (+ fused zeroing of out_t/sink/qtot) ----
#define ZFLOATS ((N_CLS + 2) * B_Q)     /* out_t + dummy sink row + qtot */
__global__ void k_meta(const u16* __restrict__ kcls, int* __restrict__ meta,
                       float* __restrict__ out_t) {
    const int nt = gridDim.x * blockDim.x;
    const float4 z = {0.0f, 0.0f, 0.0f, 0.0f};
    for (int i = blockIdx.x * blockDim.x + threadIdx.x; i < ZFLOATS / 4; i += nt)
        ((float4*)out_t)[i] = z;

    const int gid  = blockIdx.x * blockDim.x + threadIdx.x;
    const int g    = gid >> 6;
    const int lane = threadIdx.x & 63;
    if (g >= NGP) return;
    const int  cl = kcls[g * 32 + (lane & 31)];
    const int  ca = __shfl(cl, 0);
    const uint dm = (uint)(__ballot(cl != ca) & 0xffffffffull);
    const int  split = dm ? (__ffs(dm) - 1) : 32;
    const int  cb = (split < 32) ? __shfl(cl, split) : ca;
    if (lane == 0) meta[g] = ca | (cb << 11) | (split << 22);
}

// ---- main: 1-wave blocks (6400 x 64), swapped-operand MFMA, register
// double-buffered K prefetch (full unroll, static indices), fused softmax
// denominator (tot -> qtot). Barrier-free, LDS-free; XCD co-located chunks.
#define FLUSH2(C) {                                                           \
        const float v0 = racc0 + __shfl_xor(racc0, 32);                       \
        const float v1 = racc1 + __shfl_xor(racc1, 32);                       \
        if ((C) != N_CLS) { tot0 += racc0; tot1 += racc1; }                   \
        if (lhi == 0) {                                                       \
            atomicAdd(&out_t[(size_t)(C) * B_Q + q00 + l31], v0);             \
            atomicAdd(&out_t[(size_t)(C) * B_Q + q01 + l31], v1);             \
        }                                                                     \
    }

#define LOADK(DST, I) {                                                       \
        const f16* _kb = kf2 + (size_t)(g0 + (I)) * 4096 + lane * 8;          \
        _Pragma("unroll")                                                     \
        for (int kk = 0; kk < 8; ++kk) DST[kk] = *(const f16x8*)(_kb + kk * 512); \
    }

#define BODY(KB, I) {                                                         \
        const int m     = __shfl(mv, (I));      /* static lane -> readlane */ \
        const int ca    = m & 0x7FF;                                          \
        const int cb    = (m >> 11) & 0x7FF;                                  \
        const int split = m >> 22;                                            \
        f32x16 c0 = {}, c1 = {};                                              \
        _Pragma("unroll")                                                     \
        for (int kk = 0; kk < 8; ++kk) {                                      \
            c0 = __builtin_amdgcn_mfma_f32_32x32x16_f16(KB[kk], Q0[kk], c0, 0, 0, 0); \
            c1 = __builtin_amdgcn_mfma_f32_32x32x16_f16(KB[kk], Q1[kk], c1, 0, 0, 0); \
        }                                                                     \
        if (ca != cur) {                                                      \
            if (cur >= 0) FLUSH2(cur);                                        \
            racc0 = 0.0f; racc1 = 0.0f;                                       \
            cur = ca;                                                         \
        }                                                                     \
        if (split == 32) {                                                    \
            float ga = 0.f, gb = 0.f, gc = 0.f, gd = 0.f;                     \
            _Pragma("unroll")                                                 \
            for (int r = 0; r < 16; r += 2) {                                 \
                ga += __builtin_amdgcn_exp2f(c0[r]);                          \
                gb += __builtin_amdgcn_exp2f(c0[r + 1]);                      \
                gc += __builtin_amdgcn_exp2f(c1[r]);                          \
                gd += __builtin_amdgcn_exp2f(c1[r + 1]);                      \
            }                                                                 \
            racc0 += ga + gb;                                                 \
            racc1 += gc + gd;                                                 \
        } else {                                                              \
            float ga = 0.f, gb = 0.f, gc = 0.f, gd = 0.f;                     \
            float ha = 0.f, hb = 0.f, hc = 0.f, hd = 0.f;                     \
            _Pragma("unroll")                                                 \
            for (int r = 0; r < 16; r += 2) {                                 \
                const int  kr0 = ((r & 3) + 8 * (r >> 2)) + lhi4;             \
                const int  kr1 = (((r + 1) & 3) + 8 * ((r + 1) >> 2)) + lhi4; \
                const float e0  = __builtin_amdgcn_exp2f(c0[r]);              \
                const float e0b = __builtin_amdgcn_exp2f(c0[r + 1]);          \
                const float e1  = __builtin_amdgcn_exp2f(c1[r]);              \
                const float e1b = __builtin_amdgcn_exp2f(c1[r + 1]);          \
                const bool inA0 = kr0 < split;                                \
                const bool inA1 = kr1 < split;                                \
                ga += inA0 ? e0  : 0.0f;  ha += inA0 ? 0.0f : e0;             \
                gb += inA1 ? e0b : 0.0f;  hb += inA1 ? 0.0f : e0b;            \
                gc += inA0 ? e1  : 0.0f;  hc += inA0 ? 0.0f : e1;             \
                gd += inA1 ? e1b : 0.0f;  hd += inA1 ? 0.0f : e1b;            \
            }                                                                 \
            racc0 += ga + gb;                                                 \
            racc1 += gc + gd;                                                 \
            FLUSH2(cur);                                                      \
            racc0 = ha + hb;                                                  \
            racc1 = hc + hd;                                                  \
            cur = cb;                                                         \
        }                                                                     \
    }

__global__ __launch_bounds__(64)
void class_gemm7(const f16* __restrict__ kf2, const f16* __restrict__ qf2,
                 const int* __restrict__ meta, float* __restrict__ out_t,
                 float* __restrict__ qtot) {
    const int lane = threadIdx.x & 63;
    const int l31  = lane & 31;
    const int lhi  = lane >> 5;
    const int lhi4 = lhi << 2;

    // 1 wave = (chunk, qquad, wsub); 16 sibling waves of a chunk share b&7
    const int b     = blockIdx.x;           // 0..6399
    const int xcd   = b & 7;
    const int u     = b >> 3;               // 0..799
    const int chunk = xcd * (NCHUNK / 8) + (u >> 4);
    const int qquad = (u >> 2) & 3;
    const int wsub  = u & 3;
    const int g0    = chunk * GPC;

    f16x8 Q0[8], Q1[8];
    {
        const f16* qa = qf2 + (size_t)(qquad * 8 + wsub * 2) * 4096 + lane * 8;
        #pragma unroll
        for (int kk = 0; kk < 8; ++kk) {
            Q0[kk] = *(const f16x8*)(qa + kk * 512);
            Q1[kk] = *(const f16x8*)(qa + 4096 + kk * 512);
        }
    }
    const int q00 = qquad * 256 + wsub * 64;
    const int q01 = q00 + 32;

    const int mv = meta[g0 + (lane & (GPC - 1))];

    float racc0 = 0.0f, racc1 = 0.0f;
    float tot0  = 0.0f, tot1  = 0.0f;
    int cur = -1;

    f16x8 K0[8], K1[8];
    LOADK(K0, 0);
    #pragma unroll
    for (int ii = 0; ii < GPC / 2; ++ii) {
        { const int i = 2 * ii;     if (i + 1 < GPC) LOADK(K1, i + 1); BODY(K0, i); }
        { const int i = 2 * ii + 1; if (i + 1 < GPC) LOADK(K0, i + 1); BODY(K1, i); }
    }
    if (cur >= 0) FLUSH2(cur);

    // fused softmax denominator
    {
        const float t0 = tot0 + __shfl_xor(tot0, 32);
        const float t1 = tot1 + __shfl_xor(tot1, 32);
        if (lhi == 0) {
            atomicAdd(&qtot[q00 + l31], t0);
            atomicAdd(&qtot[q01 + l31], t1);
        }
    }
}

// ---- epilogue: 64x64 scaled transpose tiles; denominator from qtot ----
__global__ __launch_bounds__(256)
void k_norm_t(const float* __restrict__ out_t, const float* __restrict__ qtot,
              float* __restrict__ out) {
    __shared__ float tile[64 * 65];
    __shared__ float invq[64];
    const int tid  = threadIdx.x;
    const int w    = tid >> 6;
    const int lane = tid & 63;
    const int q0   = blockIdx.x * 64;
    const int c0   = blockIdx.y * 64;

    if (tid < 64) invq[tid] = 1.0f / qtot[q0 + tid];

    #pragma unroll
    for (int i = 0; i < 16; ++i) {
        const int cidx = c0 + w * 16 + i;
        const float v = (cidx < N_CLS) ? out_t[(size_t)cidx * B_Q + q0 + lane] : 0.0f;
        tile[lane * 65 + w * 16 + i] = v;
    }
    __syncthreads();
    #pragma unroll
    for (int j = 0; j < 16; ++j) {
        const int r    = w * 16 + j;
        const int cidx = c0 + lane;
        if (cidx < N_CLS)
            out[(size_t)(q0 + r) * N_CLS + cidx] = tile[r * 65 + lane] * invq[r];
    }
}

extern "C" void kernel_launch(void* const* d_in, const int* in_sizes, int n_in,
                              void* d_out, int out_size, void* d_ws, size_t ws_size,
                              hipStream_t stream) {
    const float* qm     = (const float*)d_in[0];
    const float* km     = (const float*)d_in[1];
    const int*   labels = (const int*)d_in[2];
    float* out = (float*)d_out;

    char* p = (char*)d_ws;
    f16*   kf2     = (f16*)p;   p += (size_t)NPAD * DIM * 2;        // 26.2 MB
    f16*   qf2     = (f16*)p;   p += (size_t)B_Q * DIM * 2;         // 256 KB
    float* out_t   = (float*)p; p += (size_t)N_CLS * B_Q * 4;       // 4.1 MB
    float* sink    = (float*)p; p += (size_t)B_Q * 4;               // dummy row 1000
    float* qtot    = (float*)p; p += (size_t)B_Q * 4;               // 4 KB
    uint*  cursor  = (uint*)p;  p += N_CLS * 4;
    u16*   kcls    = (u16*)p;   p += (size_t)NPAD * 2;              // 205 KB
    int*   meta    = (int*)p;   p += (size_t)NGP * 4;               // 12.8 KB
    int*   src     = (int*)p;   p += (size_t)NPAD * 4;              // 410 KB
    (void)sink;
    // hist128 aliases out_t: written by k_hist, consumed by k_scan, then
    // k_meta zeroes out_t+sink+qtot (stream-ordered, strictly after).
    uint*  hist128 = (uint*)out_t;                                  // 512 KB

    hipLaunchKernelGGL(k_hist, dim3(NH), dim3(256), 0, stream, labels, hist128);
    hipLaunchKernelGGL(k_scan, dim3(1), dim3(1024), 0, stream, hist128, cursor);
    hipLaunchKernelGGL(k_perm, dim3(NPAD / 256), dim3(256), 0, stream,
                       labels, cursor, src, kcls);
    hipLaunchKernelGGL(k_gather, dim3(NGP + QGRP), dim3(256), 0, stream,
                       qm, km, src, kf2, qf2);
    hipLaunchKernelGGL(k_meta, dim3((NGP * 64 + 255) / 256), dim3(256), 0, stream,
                       kcls, meta, out_t);

    hipLaunchKernelGGL(class_gemm7, dim3(16 * NCHUNK), dim3(64), 0, stream,
                       kf2, qf2, meta, out_t, qtot);

    hipLaunchKernelGGL(k_norm_t, dim3(B_Q / 64, (N_CLS + 63) / 64), dim3(256), 0, stream,
                       out_t, qtot, out);
}